// Round 4
// baseline (3589.949 us; speedup 1.0000x reference)
//
#include <hip/hip_runtime.h>

// ---------------------------------------------------------------------------
// PVRNNLayer: B=128, T=1000, D=256, Z=32, IN=256.
// Float I/O dtype (bf16 vs fp32) detected at runtime (k0) from hd bit patterns.
// (Counters show the harness data is fp32: k2_scan_f32 is the live scan.)
//
// out layout: d_seq [B][T][D] (32,768,000 elems), sum_wkls (1), wnll (1)
//
//  k1 : hdW = hd @ Whd2h^T + bias  -> stored IN-PLACE into out's d_seq region
//  k2 (fp32): persistent scan, 1 block/row, 256 thr, launch_bounds(256,1).
//      Thread j owns unit j: FULL K=256 weights in VGPRs (float4 wdh[64]),
//      dS/zS double-buffered in LDS -> ONE raw s_barrier per step, h-update
//      register-local, fast tanh/exp via v_exp_f32.
//  k2bf (bf16): same structure with packed-f16 dot2 (flag-guarded).
//  k2b: KL computed post-scan (prior path never feeds the recurrence):
//      dz = d(t-1)@Wd2z^T batched GEMM + KL reduce.
//  k3 : finalize the two scalars.
// ---------------------------------------------------------------------------

#define BB 128
#define TT 1000
#define NSEQ 32768000
#define KEPS 1e-6f

typedef _Float16 half2v __attribute__((ext_vector_type(2)));

__device__ __forceinline__ float bfu(unsigned short u) {
    union { unsigned int i; float f; } v; v.i = ((unsigned int)u) << 16; return v.f;
}
__device__ __forceinline__ unsigned short f2bf(float f) {   // RNE
    union { float f; unsigned int i; } v; v.f = f;
    unsigned int x = v.i;
    return (unsigned short)((x + 0x7fffu + ((x >> 16) & 1u)) >> 16);
}
__device__ __forceinline__ float ldf(const void* p, size_t i, int bf) {
    return bf ? bfu(((const unsigned short*)p)[i]) : ((const float*)p)[i];
}
__device__ __forceinline__ void stf(void* p, size_t i, float v, int bf) {
    if (bf) ((unsigned short*)p)[i] = f2bf(v);
    else    ((float*)p)[i] = v;
}
__device__ __forceinline__ half2v u2h2(unsigned int u) {
    union { unsigned int u; half2v h; } v; v.u = u; return v.h;
}
__device__ __forceinline__ half2v bfpair2h2(unsigned int u) {
    union { unsigned int i; float f; } lo, hi;
    lo.i = u << 16; hi.i = u & 0xffff0000u;
    half2v r; r.x = (_Float16)lo.f; r.y = (_Float16)hi.f; return r;
}
__device__ __forceinline__ unsigned short f2h_bits(float f) {
    union { _Float16 h; unsigned short u; } v; v.h = (_Float16)f; return v.u;
}

#if __has_builtin(__builtin_amdgcn_fdot2)
#define FDOT2(a, b, c) __builtin_amdgcn_fdot2((a), (b), (c), false)
#else
__device__ __forceinline__ float FDOT2(half2v a, half2v b, float c) {
    return c + (float)a.x * (float)b.x + (float)a.y * (float)b.y;
}
#endif

// fast transcendental: exp(x) and tanh(x) via single v_exp_f32 (2^x) each.
// tanh(x) = 1 - 2/(exp2(2*log2e*x)+1): saturates correctly at +-1 for |x| large.
__device__ __forceinline__ float fexp(float x) {
    float e;
    float t = x * 1.4426950408889634f;
    asm("v_exp_f32 %0, %1" : "=v"(e) : "v"(t));
    return e;
}
__device__ __forceinline__ float ftanh(float x) {
    float e, r;
    float t = x * 2.8853900817779268f;
    asm("v_exp_f32 %0, %1" : "=v"(e) : "v"(t));
    float d = e + 1.f;
    asm("v_rcp_f32 %0, %1" : "=v"(r) : "v"(d));
    return 1.f - 2.f * r;
}

// raw barrier: LDS ordering only -- global loads/stores stay in flight
// (no cross-thread global deps in the scan kernels)
#define BAR() do {                                             \
    asm volatile("s_waitcnt lgkmcnt(0)" ::: "memory");         \
    __builtin_amdgcn_s_barrier();                              \
    asm volatile("" ::: "memory");                             \
} while (0)

// ---------------------------------------------------------------------------
// k0: dtype detector.
// ---------------------------------------------------------------------------
__global__ __launch_bounds__(256) void k0_detect(
    const unsigned short* __restrict__ hd, int* __restrict__ flag)
{
    __shared__ int cnt;
    if (threadIdx.x == 0) cnt = 0;
    __syncthreads();
    int c = 0;
    for (int i = threadIdx.x; i < 2048; i += 256) {
        unsigned short u = hd[i];
        int e = (u >> 7) & 0xFF;
        c += ((e >= 112 && e <= 134) || ((u & 0x7FFF) == 0)) ? 1 : 0;
    }
    atomicAdd(&cnt, c);
    __syncthreads();
    if (threadIdx.x == 0) flag[0] = (cnt > 1700) ? 1 : 0;
}

// ---------------------------------------------------------------------------
// k1: hdW = hd @ Whd2h^T + bias -> out (d_seq region).  grid 4000 x 256 thr.
// ---------------------------------------------------------------------------
__global__ __launch_bounds__(256) void k1_gemm(
    const void* __restrict__ hd,
    const void* __restrict__ W,       // Whd2h [256][256]
    const void* __restrict__ bias,
    void* __restrict__ out,
    const int* __restrict__ flagp)
{
    const int bf = flagp[0];
    __shared__ __align__(16) float hdS[32][36];
    const int tid = threadIdx.x;
    const int j = tid;
    const long m0 = (long)blockIdx.x * 32;
    const int lm = tid >> 3;
    const int lk = (tid & 7) * 4;

    float acc[32];
#pragma unroll
    for (int m = 0; m < 32; m++) acc[m] = 0.f;

    for (int kc = 0; kc < 256; kc += 32) {
        float stage[4];
        float w[32];
        if (bf) {
            const unsigned short* hp =
                (const unsigned short*)hd + (size_t)(m0 + lm) * 256 + kc + lk;
            uint2 sv = *(const uint2*)hp;
            stage[0] = bfu((unsigned short)(sv.x & 0xffff));
            stage[1] = bfu((unsigned short)(sv.x >> 16));
            stage[2] = bfu((unsigned short)(sv.y & 0xffff));
            stage[3] = bfu((unsigned short)(sv.y >> 16));
            const unsigned short* wp =
                (const unsigned short*)W + (size_t)j * 256 + kc;
#pragma unroll
            for (int g = 0; g < 4; g++) {
                uint4 wv = *(const uint4*)(wp + g * 8);
                w[g*8+0] = bfu((unsigned short)(wv.x & 0xffff));
                w[g*8+1] = bfu((unsigned short)(wv.x >> 16));
                w[g*8+2] = bfu((unsigned short)(wv.y & 0xffff));
                w[g*8+3] = bfu((unsigned short)(wv.y >> 16));
                w[g*8+4] = bfu((unsigned short)(wv.z & 0xffff));
                w[g*8+5] = bfu((unsigned short)(wv.z >> 16));
                w[g*8+6] = bfu((unsigned short)(wv.w & 0xffff));
                w[g*8+7] = bfu((unsigned short)(wv.w >> 16));
            }
        } else {
            const float* hp = (const float*)hd + (size_t)(m0 + lm) * 256 + kc + lk;
            float4 sv = *(const float4*)hp;
            stage[0] = sv.x; stage[1] = sv.y; stage[2] = sv.z; stage[3] = sv.w;
            const float* wp = (const float*)W + (size_t)j * 256 + kc;
#pragma unroll
            for (int g = 0; g < 8; g++) {
                float4 wv = *(const float4*)(wp + g * 4);
                w[g*4+0] = wv.x; w[g*4+1] = wv.y; w[g*4+2] = wv.z; w[g*4+3] = wv.w;
            }
        }
        __syncthreads();
#pragma unroll
        for (int q = 0; q < 4; q++) hdS[lm][lk + q] = stage[q];
        __syncthreads();
#pragma unroll
        for (int m = 0; m < 32; m++) {
            float s0 = 0.f, s1 = 0.f;
#pragma unroll
            for (int k4 = 0; k4 < 8; k4++) {
                float4 a = *(const float4*)&hdS[m][k4 * 4];
                float t0 = a.x*w[k4*4+0] + a.y*w[k4*4+1];
                float t1 = a.z*w[k4*4+2] + a.w*w[k4*4+3];
                if (k4 & 1) s1 += t0 + t1; else s0 += t0 + t1;
            }
            acc[m] += s0 + s1;
        }
    }
    float bj = ldf(bias, (size_t)j, bf);
#pragma unroll
    for (int m = 0; m < 32; m++)
        stf(out, (size_t)(m0 + m) * 256 + j, acc[m] + bj, bf);
}

// ---------------------------------------------------------------------------
// k2 (fp32): persistent scan, grid=128, block=256, launch_bounds(256,1).
// Thread j owns unit j: full K=256 fp32 weights in VGPRs.  ONE barrier/step.
// Wave 1 runs the z(t+1) pipeline (lanes<32 tanh, lanes>=32 exp, shfl merge).
// ---------------------------------------------------------------------------
__global__ __launch_bounds__(256, 1) void k2_scan_f32(
    const float* __restrict__ A,
    const float* __restrict__ noise,
    const float* __restrict__ Wd2h,
    const float* __restrict__ Wz2h,
    const float* __restrict__ init_h,
    float* __restrict__ out,           // holds hdW, overwritten with d
    const int* __restrict__ flagp)
{
    if (flagp[0] != 0) return;
    const int b = blockIdx.x;
    const int tid = threadIdx.x;
    const int j = tid;
    const int l = tid & 63;
    const int w = tid >> 6;

    __shared__ __align__(16) float dS[2][256];
    __shared__ __align__(16) float zS[2][32];

    // ---- full weight row in registers: 64 float4 = 256 VGPR ----
    float4 wdh[64];
    {
        const float4* wr = (const float4*)(Wd2h + (size_t)j * 256);
#pragma unroll
        for (int k = 0; k < 64; k++) wdh[k] = wr[k];
    }
    float4 wzh[8];
    {
        const float4* wr = (const float4*)(Wz2h + (size_t)j * 32);
#pragma unroll
        for (int k = 0; k < 8; k++) wzh[k] = wr[k];
    }

    const size_t baseA = (size_t)b * TT * 64;
    const size_t baseN = (size_t)b * TT * 32;
    const size_t baseO = (size_t)b * TT * 256;

    // ---- state init ----
    float hv = init_h[(size_t)b * 256 + j];
    float h = hv;
    const float tau = (j < 128) ? 4.f : 2.f;
    const float decay = 1.f - 1.f / tau;
    const float invt = 1.f / tau;
    dS[0][j] = ftanh(hv);

    // ---- z(0) + pipeline regs (wave 1) ----
    float aVc = 0.f, nVc = 0.f;
    if (w == 1) {
        float av0 = A[baseA + l];
        float val0 = (l < 32) ? ftanh(av0) : fexp(av0);
        float nv0 = (l < 32) ? noise[baseN + l] : 0.f;
        float e0 = __shfl_down(val0, 32, 64);
        if (l < 32) zS[0][l] = val0 + nv0 * e0;
        aVc = A[baseA + 64 + l];
        nVc = (l < 32) ? noise[baseN + 32 + l] : 0.f;
    }

    float hdw_c = out[baseO + j];          // hdW(0)
    BAR();

#pragma unroll 1
    for (int t = 0; t < TT; t++) {
        // prefetches (stay in flight across the raw barrier)
        float hdw_p = 0.f;
        if (t < TT - 1) hdw_p = out[baseO + (size_t)(t + 1) * 256 + j];
        float aVp = 0.f, nVp = 0.f;
        if (w == 1 && t + 2 < TT) {
            aVp = A[baseA + (size_t)(t + 2) * 64 + l];
            nVp = (l < 32) ? noise[baseN + (size_t)(t + 2) * 32 + l] : 0.f;
        }

        // ---- matvec: P = dot(d, Wd2h_row) + dot(z, Wz2h_row) ----
        float ac[8];
#pragma unroll
        for (int i = 0; i < 8; i++) ac[i] = 0.f;
        {
            const float4* dp = (const float4*)dS[t & 1];
#pragma unroll
            for (int k = 0; k < 64; k++) {
                float4 dv = dp[k];
                float4 wv = wdh[k];
                const int a = (k & 1) << 2;
                ac[a+0] = fmaf(dv.x, wv.x, ac[a+0]);
                ac[a+1] = fmaf(dv.y, wv.y, ac[a+1]);
                ac[a+2] = fmaf(dv.z, wv.z, ac[a+2]);
                ac[a+3] = fmaf(dv.w, wv.w, ac[a+3]);
            }
            const float4* zp = (const float4*)zS[t & 1];
#pragma unroll
            for (int k = 0; k < 8; k++) {
                float4 zv = zp[k];
                float4 wv = wzh[k];
                const int a = (k & 1) << 2;
                ac[a+0] = fmaf(zv.x, wv.x, ac[a+0]);
                ac[a+1] = fmaf(zv.y, wv.y, ac[a+1]);
                ac[a+2] = fmaf(zv.z, wv.z, ac[a+2]);
                ac[a+3] = fmaf(zv.w, wv.w, ac[a+3]);
            }
        }
        float P = ((ac[0] + ac[1]) + (ac[2] + ac[3]))
                + ((ac[4] + ac[5]) + (ac[6] + ac[7]));

        // ---- h/d update: fully register-local ----
        float pre = P + hdw_c;
        h = decay * h + pre * invt;
        float dn = ftanh(h);
        out[baseO + (size_t)t * 256 + j] = dn;
        dS[(t + 1) & 1][j] = dn;

        // ---- z(t+1) pipeline (wave 1) ----
        if (w == 1 && t < TT - 1) {
            float val = (l < 32) ? ftanh(aVc) : fexp(aVc);
            float e = __shfl_down(val, 32, 64);
            if (l < 32) zS[(t + 1) & 1][l] = val + nVc * e;
            aVc = aVp; nVc = nVp;
        }
        hdw_c = hdw_p;
        BAR();                         // single barrier per step
    }
}

// ---------------------------------------------------------------------------
// k2bf (bf16): persistent scan, grid=128, block=256.  Thread j owns unit j,
// full K=256 as packed-f16 in VGPRs, v_dot2_f32_f16.  ONE barrier/step.
// ---------------------------------------------------------------------------
__global__ __launch_bounds__(256) void k2_scan_bf(
    const unsigned short* __restrict__ A,
    const unsigned short* __restrict__ noise,
    const unsigned short* __restrict__ Wd2h,
    const unsigned short* __restrict__ Wz2h,
    const unsigned short* __restrict__ init_h,
    unsigned short* __restrict__ out,           // holds hdW, overwritten with d
    const int* __restrict__ flagp)
{
    if (flagp[0] != 1) return;
    const int b = blockIdx.x;
    const int tid = threadIdx.x;
    const int j = tid;
    const int l = tid & 63;
    const int w = tid >> 6;

    __shared__ unsigned int dPk[2][128];
    __shared__ unsigned int zPk[2][16];

    half2v wdh[128];
    {
        const uint4* wr = (const uint4*)(Wd2h + (size_t)j * 256);
#pragma unroll
        for (int k = 0; k < 32; k++) {
            uint4 q = wr[k];
            wdh[k*4+0] = bfpair2h2(q.x);
            wdh[k*4+1] = bfpair2h2(q.y);
            wdh[k*4+2] = bfpair2h2(q.z);
            wdh[k*4+3] = bfpair2h2(q.w);
        }
    }
    half2v wzh[16];
    {
        const uint4* wr = (const uint4*)(Wz2h + (size_t)j * 32);
#pragma unroll
        for (int k = 0; k < 4; k++) {
            uint4 q = wr[k];
            wzh[k*4+0] = bfpair2h2(q.x);
            wzh[k*4+1] = bfpair2h2(q.y);
            wzh[k*4+2] = bfpair2h2(q.z);
            wzh[k*4+3] = bfpair2h2(q.w);
        }
    }

    float hv = bfu(init_h[(size_t)b * 256 + j]);
    float h = hv;
    const float tau = (j < 128) ? 4.f : 2.f;
    const float decay = 1.f - 1.f / tau;
    const float invt = 1.f / tau;
    {
        float d0 = ftanh(hv);
        unsigned short u16 = f2h_bits(d0);
        int p16 = __shfl_xor((int)u16, 1, 64);
        if (!(tid & 1))
            dPk[0][tid >> 1] =
                (unsigned int)u16 | (((unsigned int)(unsigned short)p16) << 16);
    }

    const size_t baseA = (size_t)b * TT * 64;
    const size_t baseN = (size_t)b * TT * 32;
    const size_t baseO = (size_t)b * TT * 256;

    float aVc = 0.f, nVc = 0.f;
    if (w == 1) {
        float av0 = bfu(A[baseA + l]);
        float val0 = (l < 32) ? ftanh(av0) : fexp(av0);
        float nv0 = (l < 32) ? bfu(noise[baseN + l]) : 0.f;
        float e0 = __shfl_down(val0, 32, 64);
        if (l < 32) {
            float z0 = val0 + nv0 * e0;
            unsigned short uz = f2h_bits(z0);
            int pz = __shfl_xor((int)uz, 1, 64);
            if (!(l & 1))
                zPk[0][l >> 1] =
                    (unsigned int)uz | (((unsigned int)(unsigned short)pz) << 16);
        }
        aVc = bfu(A[baseA + 64 + l]);
        nVc = (l < 32) ? bfu(noise[baseN + 32 + l]) : 0.f;
    }

    float hdw_c = bfu(out[baseO + j]);
    BAR();

#pragma unroll 1
    for (int t = 0; t < TT; t++) {
        float hdw_p = 0.f;
        if (t < TT - 1) hdw_p = bfu(out[baseO + (size_t)(t + 1) * 256 + j]);
        float aVp = 0.f, nVp = 0.f;
        if (w == 1 && t + 2 < TT) {
            aVp = bfu(A[baseA + (size_t)(t + 2) * 64 + l]);
            nVp = (l < 32) ? bfu(noise[baseN + (size_t)(t + 2) * 32 + l]) : 0.f;
        }

        float ac[8];
#pragma unroll
        for (int i = 0; i < 8; i++) ac[i] = 0.f;
        {
            const uint4* dp = (const uint4*)dPk[t & 1];
#pragma unroll
            for (int k = 0; k < 32; k++) {
                uint4 q = dp[k];
                const int base = (k & 1) << 2;
                ac[base+0] = FDOT2(u2h2(q.x), wdh[k*4+0], ac[base+0]);
                ac[base+1] = FDOT2(u2h2(q.y), wdh[k*4+1], ac[base+1]);
                ac[base+2] = FDOT2(u2h2(q.z), wdh[k*4+2], ac[base+2]);
                ac[base+3] = FDOT2(u2h2(q.w), wdh[k*4+3], ac[base+3]);
            }
            const uint4* zp = (const uint4*)zPk[t & 1];
#pragma unroll
            for (int k = 0; k < 4; k++) {
                uint4 q = zp[k];
                const int base = (k & 1) << 2;
                ac[base+0] = FDOT2(u2h2(q.x), wzh[k*4+0], ac[base+0]);
                ac[base+1] = FDOT2(u2h2(q.y), wzh[k*4+1], ac[base+1]);
                ac[base+2] = FDOT2(u2h2(q.z), wzh[k*4+2], ac[base+2]);
                ac[base+3] = FDOT2(u2h2(q.w), wzh[k*4+3], ac[base+3]);
            }
        }
        float P = ((ac[0] + ac[1]) + (ac[2] + ac[3]))
                + ((ac[4] + ac[5]) + (ac[6] + ac[7]));

        float pre = P + hdw_c;
        h = decay * h + pre * invt;
        float dn = ftanh(h);
        out[baseO + (size_t)t * 256 + j] = f2bf(dn);
        {
            unsigned short u16 = f2h_bits(dn);
            int p16 = __shfl_xor((int)u16, 1, 64);
            if (!(tid & 1))
                dPk[(t + 1) & 1][tid >> 1] =
                    (unsigned int)u16 | (((unsigned int)(unsigned short)p16) << 16);
        }
        if (w == 1 && t < TT - 1) {
            float val = (l < 32) ? ftanh(aVc) : fexp(aVc);
            float e = __shfl_down(val, 32, 64);
            if (l < 32) {
                float zz = val + nVc * e;
                unsigned short uz = f2h_bits(zz);
                int pz = __shfl_xor((int)uz, 1, 64);
                if (!(l & 1))
                    zPk[(t + 1) & 1][l >> 1] =
                        (unsigned int)uz | (((unsigned int)(unsigned short)pz) << 16);
            }
            aVc = aVp; nVc = nVp;
        }
        hdw_c = hdw_p;
        BAR();
    }
}

// ---------------------------------------------------------------------------
// k2b: post-scan KL.  grid 4000 x 256 thr; 32 (b,t)-rows x 64 cols.
// ---------------------------------------------------------------------------
__global__ __launch_bounds__(256) void k2b_kl(
    const void* __restrict__ dseq,
    const void* __restrict__ A,
    const void* __restrict__ in_p0,
    const void* __restrict__ Wd2z,     // [64][256]
    float* __restrict__ ws_kl,
    const int* __restrict__ flagp)
{
    const int bf = flagp[0];
    const int tid = threadIdx.x;
    const long m0 = (long)blockIdx.x * 32;

    __shared__ __align__(16) float hdS[32][36];
    __shared__ float dzS[32][64];
    __shared__ float red[256];

    const int j  = tid & 63;
    const int rg = tid >> 6;

    const int lm = tid >> 3;
    const int lk = (tid & 7) * 4;
    const long gr_lm = m0 + lm;
    const int  t_lm  = (int)(gr_lm % 1000);
    const long prow  = (t_lm == 0) ? gr_lm : gr_lm - 1;

    float acc[8];
#pragma unroll
    for (int m = 0; m < 8; m++) acc[m] = 0.f;

    for (int kc = 0; kc < 256; kc += 32) {
        float stage[4];
        float w[32];
        if (bf) {
            const unsigned short* hp =
                (const unsigned short*)dseq + (size_t)prow * 256 + kc + lk;
            uint2 sv = *(const uint2*)hp;
            stage[0] = bfu((unsigned short)(sv.x & 0xffff));
            stage[1] = bfu((unsigned short)(sv.x >> 16));
            stage[2] = bfu((unsigned short)(sv.y & 0xffff));
            stage[3] = bfu((unsigned short)(sv.y >> 16));
            const unsigned short* wp =
                (const unsigned short*)Wd2z + (size_t)j * 256 + kc;
#pragma unroll
            for (int g = 0; g < 4; g++) {
                uint4 wv = *(const uint4*)(wp + g * 8);
                w[g*8+0] = bfu((unsigned short)(wv.x & 0xffff));
                w[g*8+1] = bfu((unsigned short)(wv.x >> 16));
                w[g*8+2] = bfu((unsigned short)(wv.y & 0xffff));
                w[g*8+3] = bfu((unsigned short)(wv.y >> 16));
                w[g*8+4] = bfu((unsigned short)(wv.z & 0xffff));
                w[g*8+5] = bfu((unsigned short)(wv.z >> 16));
                w[g*8+6] = bfu((unsigned short)(wv.w & 0xffff));
                w[g*8+7] = bfu((unsigned short)(wv.w >> 16));
            }
        } else {
            const float* hp = (const float*)dseq + (size_t)prow * 256 + kc + lk;
            float4 sv = *(const float4*)hp;
            stage[0] = sv.x; stage[1] = sv.y; stage[2] = sv.z; stage[3] = sv.w;
            const float* wp = (const float*)Wd2z + (size_t)j * 256 + kc;
#pragma unroll
            for (int g = 0; g < 8; g++) {
                float4 wv = *(const float4*)(wp + g * 4);
                w[g*4+0] = wv.x; w[g*4+1] = wv.y; w[g*4+2] = wv.z; w[g*4+3] = wv.w;
            }
        }
        __syncthreads();
#pragma unroll
        for (int q = 0; q < 4; q++) hdS[lm][lk + q] = stage[q];
        __syncthreads();
#pragma unroll
        for (int m = 0; m < 8; m++) {
            const int row = rg * 8 + m;
            float s0 = 0.f, s1 = 0.f;
#pragma unroll
            for (int k4 = 0; k4 < 8; k4++) {
                float4 a = *(const float4*)&hdS[row][k4 * 4];
                float t0 = a.x*w[k4*4+0] + a.y*w[k4*4+1];
                float t1 = a.z*w[k4*4+2] + a.w*w[k4*4+3];
                if (k4 & 1) s1 += t0 + t1; else s0 += t0 + t1;
            }
            acc[m] += s0 + s1;
        }
    }
    __syncthreads();
#pragma unroll
    for (int m = 0; m < 8; m++) dzS[rg * 8 + m][j] = acc[m];
    __syncthreads();

    const int zz = tid & 31;
    const int rr = tid >> 5;
    float s = 0.f;
#pragma unroll
    for (int mm = 0; mm < 4; mm++) {
        const int m = rr * 4 + mm;
        const long gr = m0 + m;
        const int  t  = (int)(gr % 1000);
        const long bb = gr / 1000;
        float pin_mu, pin_sg;
        if (t == 0) {
            pin_mu = ldf(in_p0, (size_t)bb * 64 + zz, bf);
            pin_sg = ldf(in_p0, (size_t)bb * 64 + 32 + zz, bf);
        } else {
            pin_mu = dzS[m][zz];
            pin_sg = dzS[m][zz + 32];
        }
        float mp = tanhf(pin_mu);
        float sp = expf(pin_sg);
        float amu = ldf(A, (size_t)gr * 64 + zz, bf);
        float asg = ldf(A, (size_t)gr * 64 + 32 + zz, bf);
        float mq = tanhf(amu);
        float sq = expf(asg);
        s += logf(sp + KEPS) - logf(sq + KEPS) - 0.5f
           + 0.5f * (mq*mq + sq*sq - 2.f*mq*mp + mp*mp) / (sp*sp + KEPS);
    }
    red[tid] = s;
    __syncthreads();
    for (int off = 128; off > 0; off >>= 1) {
        if (tid < off) red[tid] += red[tid + off];
        __syncthreads();
    }
    if (tid == 0) atomicAdd(ws_kl, red[0]);
}

// ---------------------------------------------------------------------------
// k3: scalars.
// ---------------------------------------------------------------------------
__global__ __launch_bounds__(256) void k3_final(
    const void* __restrict__ init_h,
    const void* __restrict__ init_mu,
    const float* __restrict__ ws_kl,
    void* __restrict__ out,
    const int* __restrict__ flagp)
{
    const int bf = flagp[0];
    __shared__ float red[256];
    const int tid = threadIdx.x;
    float s = 0.f;
    for (int i = tid; i < BB * 256; i += 256) {
        float d = ldf(init_h, (size_t)i, bf) - ldf(init_mu, (size_t)(i & 255), bf);
        s += 0.5f * d * d;
    }
    red[tid] = s;
    __syncthreads();
    for (int off = 128; off > 0; off >>= 1) {
        if (tid < off) red[tid] += red[tid + off];
        __syncthreads();
    }
    if (tid == 0) {
        float tot = red[0] + (float)(BB * 256) * 0.91893853320467274f;
        stf(out, (size_t)NSEQ,     ws_kl[0] * (0.001f / 32.f), bf);
        stf(out, (size_t)NSEQ + 1, 0.001f * tot / 256.f, bf);
    }
}

// ---------------------------------------------------------------------------
extern "C" void kernel_launch(void* const* d_in, const int* in_sizes, int n_in,
                              void* d_out, int out_size, void* d_ws, size_t ws_size,
                              hipStream_t stream)
{
    float* wskl = (float*)d_ws;
    int*   flag = ((int*)d_ws) + 1;

    hipMemsetAsync(d_ws, 0, 8, stream);

    k0_detect<<<1, 256, 0, stream>>>((const unsigned short*)d_in[0], flag);

    k1_gemm<<<(BB * TT) / 32, 256, 0, stream>>>(d_in[0], d_in[7], d_in[8],
                                                d_out, flag);

    // recurrent scan: fp32 fast path + bf16 path (flag-guarded)
    k2_scan_f32<<<BB, 256, 0, stream>>>(
        (const float*)d_in[1], (const float*)d_in[3],
        (const float*)d_in[4], (const float*)d_in[5],
        (const float*)d_in[9], (float*)d_out, flag);
    k2_scan_bf<<<BB, 256, 0, stream>>>(
        (const unsigned short*)d_in[1], (const unsigned short*)d_in[3],
        (const unsigned short*)d_in[4], (const unsigned short*)d_in[5],
        (const unsigned short*)d_in[9], (unsigned short*)d_out, flag);

    // post-scan KL: dz GEMM + reduce
    k2b_kl<<<(BB * TT) / 32, 256, 0, stream>>>(d_out, d_in[1], d_in[2],
                                               d_in[6], wskl, flag);

    k3_final<<<1, 256, 0, stream>>>(d_in[9], d_in[10], wskl, d_out, flag);
}

// Round 5
// 1897.898 us; speedup vs baseline: 1.8915x; 1.8915x over previous
//
#include <hip/hip_runtime.h>

// ---------------------------------------------------------------------------
// PVRNNLayer: B=128, T=1000, D=256, Z=32, IN=256.  (harness data: fp32)
//
// out layout: d_seq [B][T][D], sum_wkls (1), wnll (1)
//
//  k1 : hdW = hd @ Whd2h^T + bias -> IN-PLACE into out's d_seq region
//  k2 : persistent scan, 1 block/row, 512 thr, 2-phase, raw barriers.
//       KEY FIX (r4 post-mortem): weight loads passed through opaque inline
//       asm so LLVM cannot rematerialize them inside the t-loop -- weights
//       become truly VGPR-resident (r2-r4 re-fetched 256KB/step from L2).
//  k2b: KL post-scan (prior path never feeds the recurrence).
//  k3 : finalize scalars.
// ---------------------------------------------------------------------------

#define BB 128
#define TT 1000
#define NSEQ 32768000
#define KEPS 1e-6f

typedef _Float16 half2v __attribute__((ext_vector_type(2)));

__device__ __forceinline__ float bfu(unsigned short u) {
    union { unsigned int i; float f; } v; v.i = ((unsigned int)u) << 16; return v.f;
}
__device__ __forceinline__ unsigned short f2bf(float f) {   // RNE
    union { float f; unsigned int i; } v; v.f = f;
    unsigned int x = v.i;
    return (unsigned short)((x + 0x7fffu + ((x >> 16) & 1u)) >> 16);
}
__device__ __forceinline__ float ldf(const void* p, size_t i, int bf) {
    return bf ? bfu(((const unsigned short*)p)[i]) : ((const float*)p)[i];
}
__device__ __forceinline__ void stf(void* p, size_t i, float v, int bf) {
    if (bf) ((unsigned short*)p)[i] = f2bf(v);
    else    ((float*)p)[i] = v;
}
__device__ __forceinline__ half2v u2h2(unsigned int u) {
    union { unsigned int u; half2v h; } v; v.u = u; return v.h;
}
__device__ __forceinline__ half2v bfpair2h2(unsigned int u) {
    union { unsigned int i; float f; } lo, hi;
    lo.i = u << 16; hi.i = u & 0xffff0000u;
    half2v r; r.x = (_Float16)lo.f; r.y = (_Float16)hi.f; return r;
}
__device__ __forceinline__ unsigned short f2h_bits(float f) {
    union { _Float16 h; unsigned short u; } v; v.h = (_Float16)f; return v.u;
}

#if __has_builtin(__builtin_amdgcn_fdot2)
#define FDOT2(a, b, c) __builtin_amdgcn_fdot2((a), (b), (c), false)
#else
__device__ __forceinline__ float FDOT2(half2v a, half2v b, float c) {
    return c + (float)a.x * (float)b.x + (float)a.y * (float)b.y;
}
#endif

// Opaque redefinition: allocator cannot rematerialize (re-load) past this,
// so the value must stay VGPR-resident across the scan loop.
#define KEEPF(x)  asm volatile("" : "+v"(x))
#define KEEP4(v)  do { KEEPF(v.x); KEEPF(v.y); KEEPF(v.z); KEEPF(v.w); } while (0)

// fast transcendental via v_exp_f32 (2^x).
__device__ __forceinline__ float fexp(float x) {
    float e;
    float t = x * 1.4426950408889634f;
    asm("v_exp_f32 %0, %1" : "=v"(e) : "v"(t));
    return e;
}
__device__ __forceinline__ float ftanh(float x) {
    float e, r;
    float t = x * 2.8853900817779268f;
    asm("v_exp_f32 %0, %1" : "=v"(e) : "v"(t));
    float d = e + 1.f;
    asm("v_rcp_f32 %0, %1" : "=v"(r) : "v"(d));
    return 1.f - 2.f * r;
}

// raw barrier: LDS ordering only -- global loads/stores stay in flight
#define BAR() do {                                             \
    asm volatile("s_waitcnt lgkmcnt(0)" ::: "memory");         \
    __builtin_amdgcn_s_barrier();                              \
    asm volatile("" ::: "memory");                             \
} while (0)

// ---------------------------------------------------------------------------
// k0: dtype detector.
// ---------------------------------------------------------------------------
__global__ __launch_bounds__(256) void k0_detect(
    const unsigned short* __restrict__ hd, int* __restrict__ flag)
{
    __shared__ int cnt;
    if (threadIdx.x == 0) cnt = 0;
    __syncthreads();
    int c = 0;
    for (int i = threadIdx.x; i < 2048; i += 256) {
        unsigned short u = hd[i];
        int e = (u >> 7) & 0xFF;
        c += ((e >= 112 && e <= 134) || ((u & 0x7FFF) == 0)) ? 1 : 0;
    }
    atomicAdd(&cnt, c);
    __syncthreads();
    if (threadIdx.x == 0) flag[0] = (cnt > 1700) ? 1 : 0;
}

// ---------------------------------------------------------------------------
// k1: hdW = hd @ Whd2h^T + bias -> out (d_seq region).  grid 4000 x 256 thr.
// ---------------------------------------------------------------------------
__global__ __launch_bounds__(256) void k1_gemm(
    const void* __restrict__ hd,
    const void* __restrict__ W,       // Whd2h [256][256]
    const void* __restrict__ bias,
    void* __restrict__ out,
    const int* __restrict__ flagp)
{
    const int bf = flagp[0];
    __shared__ __align__(16) float hdS[32][36];
    const int tid = threadIdx.x;
    const int j = tid;
    const long m0 = (long)blockIdx.x * 32;
    const int lm = tid >> 3;
    const int lk = (tid & 7) * 4;

    float acc[32];
#pragma unroll
    for (int m = 0; m < 32; m++) acc[m] = 0.f;

    for (int kc = 0; kc < 256; kc += 32) {
        float stage[4];
        float w[32];
        if (bf) {
            const unsigned short* hp =
                (const unsigned short*)hd + (size_t)(m0 + lm) * 256 + kc + lk;
            uint2 sv = *(const uint2*)hp;
            stage[0] = bfu((unsigned short)(sv.x & 0xffff));
            stage[1] = bfu((unsigned short)(sv.x >> 16));
            stage[2] = bfu((unsigned short)(sv.y & 0xffff));
            stage[3] = bfu((unsigned short)(sv.y >> 16));
            const unsigned short* wp =
                (const unsigned short*)W + (size_t)j * 256 + kc;
#pragma unroll
            for (int g = 0; g < 4; g++) {
                uint4 wv = *(const uint4*)(wp + g * 8);
                w[g*8+0] = bfu((unsigned short)(wv.x & 0xffff));
                w[g*8+1] = bfu((unsigned short)(wv.x >> 16));
                w[g*8+2] = bfu((unsigned short)(wv.y & 0xffff));
                w[g*8+3] = bfu((unsigned short)(wv.y >> 16));
                w[g*8+4] = bfu((unsigned short)(wv.z & 0xffff));
                w[g*8+5] = bfu((unsigned short)(wv.z >> 16));
                w[g*8+6] = bfu((unsigned short)(wv.w & 0xffff));
                w[g*8+7] = bfu((unsigned short)(wv.w >> 16));
            }
        } else {
            const float* hp = (const float*)hd + (size_t)(m0 + lm) * 256 + kc + lk;
            float4 sv = *(const float4*)hp;
            stage[0] = sv.x; stage[1] = sv.y; stage[2] = sv.z; stage[3] = sv.w;
            const float* wp = (const float*)W + (size_t)j * 256 + kc;
#pragma unroll
            for (int g = 0; g < 8; g++) {
                float4 wv = *(const float4*)(wp + g * 4);
                w[g*4+0] = wv.x; w[g*4+1] = wv.y; w[g*4+2] = wv.z; w[g*4+3] = wv.w;
            }
        }
        __syncthreads();
#pragma unroll
        for (int q = 0; q < 4; q++) hdS[lm][lk + q] = stage[q];
        __syncthreads();
#pragma unroll
        for (int m = 0; m < 32; m++) {
            float s0 = 0.f, s1 = 0.f;
#pragma unroll
            for (int k4 = 0; k4 < 8; k4++) {
                float4 a = *(const float4*)&hdS[m][k4 * 4];
                float t0 = a.x*w[k4*4+0] + a.y*w[k4*4+1];
                float t1 = a.z*w[k4*4+2] + a.w*w[k4*4+3];
                if (k4 & 1) s1 += t0 + t1; else s0 += t0 + t1;
            }
            acc[m] += s0 + s1;
        }
    }
    float bj = ldf(bias, (size_t)j, bf);
#pragma unroll
    for (int m = 0; m < 32; m++)
        stf(out, (size_t)(m0 + m) * 256 + j, acc[m] + bj, bf);
}

// ---------------------------------------------------------------------------
// k2 (fp32): persistent scan, grid=128, block=512 (8 waves), 2-phase.
// thread -> (j = tid&255, half = tid>>8); 128 weight floats per thread,
// forced VGPR-resident via KEEP4.  Raw barriers; z pipeline on thr 256..287.
// ---------------------------------------------------------------------------
__global__ __launch_bounds__(512, 2) void k2_scan_f32(
    const float* __restrict__ A,
    const float* __restrict__ noise,
    const float* __restrict__ Wd2h,
    const float* __restrict__ Wz2h,
    const float* __restrict__ init_h,
    float* __restrict__ out,           // holds hdW, overwritten with d
    const int* __restrict__ flagp)
{
    if (flagp[0] != 0) return;
    const int b = blockIdx.x;
    const int tid = threadIdx.x;
    const int j = tid & 255;
    const int half = tid >> 8;
    const int isz = (tid >= 256 && tid < 288);
    const int zi = tid & 31;

    __shared__ __align__(16) float dS[2][256];
    __shared__ __align__(16) float zS[2][32];
    __shared__ float pp[2][256];

    // ---- weights: 32 float4 = 128 VGPR, pinned via opaque asm ----
    float4 wdh[32];
    {
        const float4* wr = (const float4*)(Wd2h + (size_t)j * 256 + half * 128);
#pragma unroll
        for (int k = 0; k < 32; k++) wdh[k] = wr[k];
#pragma unroll
        for (int k = 0; k < 32; k++) KEEP4(wdh[k]);
    }
    float4 wzh[4];
    {
        const float4* wr = (const float4*)(Wz2h + (size_t)j * 32 + half * 16);
#pragma unroll
        for (int k = 0; k < 4; k++) wzh[k] = wr[k];
#pragma unroll
        for (int k = 0; k < 4; k++) KEEP4(wzh[k]);
    }

    const size_t baseA = (size_t)b * TT * 64;
    const size_t baseN = (size_t)b * TT * 32;
    const size_t baseO = (size_t)b * TT * 256;

    // ---- state init ----
    float h = 0.f, decay = 0.f, invt = 0.f;
    if (half == 0) {
        float hv = init_h[(size_t)b * 256 + j];
        h = hv;
        float tau = (j < 128) ? 4.f : 2.f;
        decay = 1.f - 1.f / tau;
        invt = 1.f / tau;
        dS[0][j] = ftanh(hv);
    }

    // ---- z(0) + pipeline regs (threads 256..319 as one wave) ----
    const int zw = (tid >> 6) == 4;        // wave 4: lanes 0..63
    const int l = tid & 63;
    float aVc = 0.f, nVc = 0.f;
    if (zw) {
        float av0 = A[baseA + l];
        float val0 = (l < 32) ? ftanh(av0) : fexp(av0);
        float nv0 = (l < 32) ? noise[baseN + l] : 0.f;
        float e0 = __shfl_down(val0, 32, 64);
        if (l < 32) zS[0][l] = val0 + nv0 * e0;
        aVc = A[baseA + 64 + l];
        nVc = (l < 32) ? noise[baseN + 32 + l] : 0.f;
    }

    float hdw_c = 0.f;
    if (half == 0) hdw_c = out[baseO + j];     // hdW(0)
    BAR();

#pragma unroll 1
    for (int t = 0; t < TT; t++) {
        // prefetches (stay in flight across raw barriers)
        float hdw_p = 0.f;
        if (t < TT - 1 && half == 0)
            hdw_p = out[baseO + (size_t)(t + 1) * 256 + j];
        float aVp = 0.f, nVp = 0.f;
        if (zw && t + 2 < TT) {
            aVp = A[baseA + (size_t)(t + 2) * 64 + l];
            nVp = (l < 32) ? noise[baseN + (size_t)(t + 2) * 32 + l] : 0.f;
        }

        // ---- phase A: partial P over this half's K-range ----
        float ac[8];
#pragma unroll
        for (int i = 0; i < 8; i++) ac[i] = 0.f;
        {
            const float4* dp = (const float4*)(dS[t & 1] + half * 128);
#pragma unroll
            for (int k = 0; k < 32; k++) {
                float4 dv = dp[k];
                float4 wv = wdh[k];
                const int a = (k & 1) << 2;
                ac[a+0] = fmaf(dv.x, wv.x, ac[a+0]);
                ac[a+1] = fmaf(dv.y, wv.y, ac[a+1]);
                ac[a+2] = fmaf(dv.z, wv.z, ac[a+2]);
                ac[a+3] = fmaf(dv.w, wv.w, ac[a+3]);
            }
            const float4* zp = (const float4*)(zS[t & 1] + half * 16);
#pragma unroll
            for (int k = 0; k < 4; k++) {
                float4 zv = zp[k];
                float4 wv = wzh[k];
                const int a = (k & 1) << 2;
                ac[a+0] = fmaf(zv.x, wv.x, ac[a+0]);
                ac[a+1] = fmaf(zv.y, wv.y, ac[a+1]);
                ac[a+2] = fmaf(zv.z, wv.z, ac[a+2]);
                ac[a+3] = fmaf(zv.w, wv.w, ac[a+3]);
            }
        }
        pp[half][j] = ((ac[0] + ac[1]) + (ac[2] + ac[3]))
                    + ((ac[4] + ac[5]) + (ac[6] + ac[7]));
        BAR();                                 // b1 (pp ready)

        // ---- phase D: h/d update (half 0) || z(t+1) pipeline (wave 4) ----
        if (half == 0) {
            float pre = pp[0][j] + pp[1][j] + hdw_c;
            h = decay * h + pre * invt;
            float dn = ftanh(h);
            dS[(t + 1) & 1][j] = dn;
            out[baseO + (size_t)t * 256 + j] = dn;
        }
        if (zw && t < TT - 1) {
            float val = (l < 32) ? ftanh(aVc) : fexp(aVc);
            float e = __shfl_down(val, 32, 64);
            if (l < 32) zS[(t + 1) & 1][l] = val + nVc * e;
            aVc = aVp; nVc = nVp;
        }
        hdw_c = hdw_p;
        BAR();                                 // b2 (dS/zS ready)
    }
}

// ---------------------------------------------------------------------------
// k2bf (bf16): flag-guarded fallback (unused on fp32 harness data).
// ---------------------------------------------------------------------------
__global__ __launch_bounds__(256) void k2_scan_bf(
    const unsigned short* __restrict__ A,
    const unsigned short* __restrict__ noise,
    const unsigned short* __restrict__ Wd2h,
    const unsigned short* __restrict__ Wz2h,
    const unsigned short* __restrict__ init_h,
    unsigned short* __restrict__ out,
    const int* __restrict__ flagp)
{
    if (flagp[0] != 1) return;
    const int b = blockIdx.x;
    const int tid = threadIdx.x;
    const int j = tid;
    const int l = tid & 63;
    const int w = tid >> 6;

    __shared__ unsigned int dPk[2][128];
    __shared__ unsigned int zPk[2][16];

    half2v wdh[128];
    {
        const uint4* wr = (const uint4*)(Wd2h + (size_t)j * 256);
#pragma unroll
        for (int k = 0; k < 32; k++) {
            uint4 q = wr[k];
            wdh[k*4+0] = bfpair2h2(q.x);
            wdh[k*4+1] = bfpair2h2(q.y);
            wdh[k*4+2] = bfpair2h2(q.z);
            wdh[k*4+3] = bfpair2h2(q.w);
        }
    }
    half2v wzh[16];
    {
        const uint4* wr = (const uint4*)(Wz2h + (size_t)j * 32);
#pragma unroll
        for (int k = 0; k < 4; k++) {
            uint4 q = wr[k];
            wzh[k*4+0] = bfpair2h2(q.x);
            wzh[k*4+1] = bfpair2h2(q.y);
            wzh[k*4+2] = bfpair2h2(q.z);
            wzh[k*4+3] = bfpair2h2(q.w);
        }
    }

    float hv = bfu(init_h[(size_t)b * 256 + j]);
    float h = hv;
    const float tau = (j < 128) ? 4.f : 2.f;
    const float decay = 1.f - 1.f / tau;
    const float invt = 1.f / tau;
    {
        float d0 = ftanh(hv);
        unsigned short u16 = f2h_bits(d0);
        int p16 = __shfl_xor((int)u16, 1, 64);
        if (!(tid & 1))
            dPk[0][tid >> 1] =
                (unsigned int)u16 | (((unsigned int)(unsigned short)p16) << 16);
    }

    const size_t baseA = (size_t)b * TT * 64;
    const size_t baseN = (size_t)b * TT * 32;
    const size_t baseO = (size_t)b * TT * 256;

    float aVc = 0.f, nVc = 0.f;
    if (w == 1) {
        float av0 = bfu(A[baseA + l]);
        float val0 = (l < 32) ? ftanh(av0) : fexp(av0);
        float nv0 = (l < 32) ? bfu(noise[baseN + l]) : 0.f;
        float e0 = __shfl_down(val0, 32, 64);
        if (l < 32) {
            float z0 = val0 + nv0 * e0;
            unsigned short uz = f2h_bits(z0);
            int pz = __shfl_xor((int)uz, 1, 64);
            if (!(l & 1))
                zPk[0][l >> 1] =
                    (unsigned int)uz | (((unsigned int)(unsigned short)pz) << 16);
        }
        aVc = bfu(A[baseA + 64 + l]);
        nVc = (l < 32) ? bfu(noise[baseN + 32 + l]) : 0.f;
    }

    float hdw_c = bfu(out[baseO + j]);
    BAR();

#pragma unroll 1
    for (int t = 0; t < TT; t++) {
        float hdw_p = 0.f;
        if (t < TT - 1) hdw_p = bfu(out[baseO + (size_t)(t + 1) * 256 + j]);
        float aVp = 0.f, nVp = 0.f;
        if (w == 1 && t + 2 < TT) {
            aVp = bfu(A[baseA + (size_t)(t + 2) * 64 + l]);
            nVp = (l < 32) ? bfu(noise[baseN + (size_t)(t + 2) * 32 + l]) : 0.f;
        }

        float ac[8];
#pragma unroll
        for (int i = 0; i < 8; i++) ac[i] = 0.f;
        {
            const uint4* dp = (const uint4*)dPk[t & 1];
#pragma unroll
            for (int k = 0; k < 32; k++) {
                uint4 q = dp[k];
                const int base = (k & 1) << 2;
                ac[base+0] = FDOT2(u2h2(q.x), wdh[k*4+0], ac[base+0]);
                ac[base+1] = FDOT2(u2h2(q.y), wdh[k*4+1], ac[base+1]);
                ac[base+2] = FDOT2(u2h2(q.z), wdh[k*4+2], ac[base+2]);
                ac[base+3] = FDOT2(u2h2(q.w), wdh[k*4+3], ac[base+3]);
            }
            const uint4* zp = (const uint4*)zPk[t & 1];
#pragma unroll
            for (int k = 0; k < 4; k++) {
                uint4 q = zp[k];
                const int base = (k & 1) << 2;
                ac[base+0] = FDOT2(u2h2(q.x), wzh[k*4+0], ac[base+0]);
                ac[base+1] = FDOT2(u2h2(q.y), wzh[k*4+1], ac[base+1]);
                ac[base+2] = FDOT2(u2h2(q.z), wzh[k*4+2], ac[base+2]);
                ac[base+3] = FDOT2(u2h2(q.w), wzh[k*4+3], ac[base+3]);
            }
        }
        float P = ((ac[0] + ac[1]) + (ac[2] + ac[3]))
                + ((ac[4] + ac[5]) + (ac[6] + ac[7]));

        float pre = P + hdw_c;
        h = decay * h + pre * invt;
        float dn = ftanh(h);
        out[baseO + (size_t)t * 256 + j] = f2bf(dn);
        {
            unsigned short u16 = f2h_bits(dn);
            int p16 = __shfl_xor((int)u16, 1, 64);
            if (!(tid & 1))
                dPk[(t + 1) & 1][tid >> 1] =
                    (unsigned int)u16 | (((unsigned int)(unsigned short)p16) << 16);
        }
        if (w == 1 && t < TT - 1) {
            float val = (l < 32) ? ftanh(aVc) : fexp(aVc);
            float e = __shfl_down(val, 32, 64);
            if (l < 32) {
                float zz = val + nVc * e;
                unsigned short uz = f2h_bits(zz);
                int pz = __shfl_xor((int)uz, 1, 64);
                if (!(l & 1))
                    zPk[(t + 1) & 1][l >> 1] =
                        (unsigned int)uz | (((unsigned int)(unsigned short)pz) << 16);
            }
            aVc = aVp; nVc = nVp;
        }
        hdw_c = hdw_p;
        BAR();
    }
}

// ---------------------------------------------------------------------------
// k2b: post-scan KL.  grid 4000 x 256 thr; 32 (b,t)-rows x 64 cols.
// ---------------------------------------------------------------------------
__global__ __launch_bounds__(256) void k2b_kl(
    const void* __restrict__ dseq,
    const void* __restrict__ A,
    const void* __restrict__ in_p0,
    const void* __restrict__ Wd2z,     // [64][256]
    float* __restrict__ ws_kl,
    const int* __restrict__ flagp)
{
    const int bf = flagp[0];
    const int tid = threadIdx.x;
    const long m0 = (long)blockIdx.x * 32;

    __shared__ __align__(16) float hdS[32][36];
    __shared__ float dzS[32][64];
    __shared__ float red[256];

    const int j  = tid & 63;
    const int rg = tid >> 6;

    const int lm = tid >> 3;
    const int lk = (tid & 7) * 4;
    const long gr_lm = m0 + lm;
    const int  t_lm  = (int)(gr_lm % 1000);
    const long prow  = (t_lm == 0) ? gr_lm : gr_lm - 1;

    float acc[8];
#pragma unroll
    for (int m = 0; m < 8; m++) acc[m] = 0.f;

    for (int kc = 0; kc < 256; kc += 32) {
        float stage[4];
        float w[32];
        if (bf) {
            const unsigned short* hp =
                (const unsigned short*)dseq + (size_t)prow * 256 + kc + lk;
            uint2 sv = *(const uint2*)hp;
            stage[0] = bfu((unsigned short)(sv.x & 0xffff));
            stage[1] = bfu((unsigned short)(sv.x >> 16));
            stage[2] = bfu((unsigned short)(sv.y & 0xffff));
            stage[3] = bfu((unsigned short)(sv.y >> 16));
            const unsigned short* wp =
                (const unsigned short*)Wd2z + (size_t)j * 256 + kc;
#pragma unroll
            for (int g = 0; g < 4; g++) {
                uint4 wv = *(const uint4*)(wp + g * 8);
                w[g*8+0] = bfu((unsigned short)(wv.x & 0xffff));
                w[g*8+1] = bfu((unsigned short)(wv.x >> 16));
                w[g*8+2] = bfu((unsigned short)(wv.y & 0xffff));
                w[g*8+3] = bfu((unsigned short)(wv.y >> 16));
                w[g*8+4] = bfu((unsigned short)(wv.z & 0xffff));
                w[g*8+5] = bfu((unsigned short)(wv.z >> 16));
                w[g*8+6] = bfu((unsigned short)(wv.w & 0xffff));
                w[g*8+7] = bfu((unsigned short)(wv.w >> 16));
            }
        } else {
            const float* hp = (const float*)dseq + (size_t)prow * 256 + kc + lk;
            float4 sv = *(const float4*)hp;
            stage[0] = sv.x; stage[1] = sv.y; stage[2] = sv.z; stage[3] = sv.w;
            const float* wp = (const float*)Wd2z + (size_t)j * 256 + kc;
#pragma unroll
            for (int g = 0; g < 8; g++) {
                float4 wv = *(const float4*)(wp + g * 4);
                w[g*4+0] = wv.x; w[g*4+1] = wv.y; w[g*4+2] = wv.z; w[g*4+3] = wv.w;
            }
        }
        __syncthreads();
#pragma unroll
        for (int q = 0; q < 4; q++) hdS[lm][lk + q] = stage[q];
        __syncthreads();
#pragma unroll
        for (int m = 0; m < 8; m++) {
            const int row = rg * 8 + m;
            float s0 = 0.f, s1 = 0.f;
#pragma unroll
            for (int k4 = 0; k4 < 8; k4++) {
                float4 a = *(const float4*)&hdS[row][k4 * 4];
                float t0 = a.x*w[k4*4+0] + a.y*w[k4*4+1];
                float t1 = a.z*w[k4*4+2] + a.w*w[k4*4+3];
                if (k4 & 1) s1 += t0 + t1; else s0 += t0 + t1;
            }
            acc[m] += s0 + s1;
        }
    }
    __syncthreads();
#pragma unroll
    for (int m = 0; m < 8; m++) dzS[rg * 8 + m][j] = acc[m];
    __syncthreads();

    const int zz = tid & 31;
    const int rr = tid >> 5;
    float s = 0.f;
#pragma unroll
    for (int mm = 0; mm < 4; mm++) {
        const int m = rr * 4 + mm;
        const long gr = m0 + m;
        const int  t  = (int)(gr % 1000);
        const long bb = gr / 1000;
        float pin_mu, pin_sg;
        if (t == 0) {
            pin_mu = ldf(in_p0, (size_t)bb * 64 + zz, bf);
            pin_sg = ldf(in_p0, (size_t)bb * 64 + 32 + zz, bf);
        } else {
            pin_mu = dzS[m][zz];
            pin_sg = dzS[m][zz + 32];
        }
        float mp = tanhf(pin_mu);
        float sp = expf(pin_sg);
        float amu = ldf(A, (size_t)gr * 64 + zz, bf);
        float asg = ldf(A, (size_t)gr * 64 + 32 + zz, bf);
        float mq = tanhf(amu);
        float sq = expf(asg);
        s += logf(sp + KEPS) - logf(sq + KEPS) - 0.5f
           + 0.5f * (mq*mq + sq*sq - 2.f*mq*mp + mp*mp) / (sp*sp + KEPS);
    }
    red[tid] = s;
    __syncthreads();
    for (int off = 128; off > 0; off >>= 1) {
        if (tid < off) red[tid] += red[tid + off];
        __syncthreads();
    }
    if (tid == 0) atomicAdd(ws_kl, red[0]);
}

// ---------------------------------------------------------------------------
// k3: scalars.
// ---------------------------------------------------------------------------
__global__ __launch_bounds__(256) void k3_final(
    const void* __restrict__ init_h,
    const void* __restrict__ init_mu,
    const float* __restrict__ ws_kl,
    void* __restrict__ out,
    const int* __restrict__ flagp)
{
    const int bf = flagp[0];
    __shared__ float red[256];
    const int tid = threadIdx.x;
    float s = 0.f;
    for (int i = tid; i < BB * 256; i += 256) {
        float d = ldf(init_h, (size_t)i, bf) - ldf(init_mu, (size_t)(i & 255), bf);
        s += 0.5f * d * d;
    }
    red[tid] = s;
    __syncthreads();
    for (int off = 128; off > 0; off >>= 1) {
        if (tid < off) red[tid] += red[tid + off];
        __syncthreads();
    }
    if (tid == 0) {
        float tot = red[0] + (float)(BB * 256) * 0.91893853320467274f;
        stf(out, (size_t)NSEQ,     ws_kl[0] * (0.001f / 32.f), bf);
        stf(out, (size_t)NSEQ + 1, 0.001f * tot / 256.f, bf);
    }
}

// ---------------------------------------------------------------------------
extern "C" void kernel_launch(void* const* d_in, const int* in_sizes, int n_in,
                              void* d_out, int out_size, void* d_ws, size_t ws_size,
                              hipStream_t stream)
{
    float* wskl = (float*)d_ws;
    int*   flag = ((int*)d_ws) + 1;

    hipMemsetAsync(d_ws, 0, 8, stream);

    k0_detect<<<1, 256, 0, stream>>>((const unsigned short*)d_in[0], flag);

    k1_gemm<<<(BB * TT) / 32, 256, 0, stream>>>(d_in[0], d_in[7], d_in[8],
                                                d_out, flag);

    // recurrent scan: fp32 fast path (weights pinned in VGPRs) + bf16 path
    k2_scan_f32<<<BB, 512, 0, stream>>>(
        (const float*)d_in[1], (const float*)d_in[3],
        (const float*)d_in[4], (const float*)d_in[5],
        (const float*)d_in[9], (float*)d_out, flag);
    k2_scan_bf<<<BB, 256, 0, stream>>>(
        (const unsigned short*)d_in[1], (const unsigned short*)d_in[3],
        (const unsigned short*)d_in[4], (const unsigned short*)d_in[5],
        (const unsigned short*)d_in[9], (unsigned short*)d_out, flag);

    // post-scan KL: dz GEMM + reduce
    k2b_kl<<<(BB * TT) / 32, 256, 0, stream>>>(d_out, d_in[1], d_in[2],
                                               d_in[6], wskl, flag);

    k3_final<<<1, 256, 0, stream>>>(d_in[9], d_in[10], wskl, d_out, flag);
}